// Round 1
// baseline (428.913 us; speedup 1.0000x reference)
//
#include <hip/hip_runtime.h>
#include <math.h>

// ArcFaceLoss: B=512, D=512, C=100000, margin=0.5, scale=64
// Pipeline:
//   1) pack_x:    normalize x rows -> bf16, prepacked chunk-major layout for global_load_lds
//   2) cosphi:    per-row fp32-accurate cos_t / phi_t (gather of 512 weight rows)
//   3) gemm_lse:  fused bf16-MFMA GEMM + exp(64*cos-64) row-sum (fixed max offset 64),
//                 weight normalization fused into LDS staging (read weight from HBM ONCE)
//   4) finalize:  corrected sum (-e_cos + e_phi), lse = 64 + log(S), mean over batch

#define NB 512
#define ND 512
#define NC 100000
#define BK 32
#define NCHUNK 16          // ND / BK
#define CT 64              // classes per block
#define FSCALE 64.0f
#define C_COS_M 0.8775825618903728f
#define C_SIN_M 0.479425538604203f
#define C_TH  (-0.8775825618903728f)   // cos(pi - m)
#define C_MM  0.2397127693021015f      // sin(pi - m) * m

typedef __bf16 bf16x8 __attribute__((ext_vector_type(8)));
typedef __bf16 bf16x4 __attribute__((ext_vector_type(4)));
typedef float  f32x4  __attribute__((ext_vector_type(4)));
typedef __attribute__((address_space(1))) unsigned int GU;
typedef __attribute__((address_space(3))) unsigned int LU;

// ---------------- 1) normalize + pack x ----------------
// xp layout: [chunk=k/32][row][k%32] bf16, so each 32K-chunk of all 512 rows is
// one contiguous 32KB block -> global_load_lds-friendly.
__global__ void pack_x_kernel(const float* __restrict__ x, __bf16* __restrict__ xp) {
  const int b = blockIdx.x;
  const int t = threadIdx.x;                   // 0..127
  float4 v = reinterpret_cast<const float4*>(x + (size_t)b * ND)[t];
  float ss = v.x*v.x + v.y*v.y + v.z*v.z + v.w*v.w;
  #pragma unroll
  for (int m = 1; m < 64; m <<= 1) ss += __shfl_xor(ss, m);
  __shared__ float sred[2];
  if ((t & 63) == 0) sred[t >> 6] = ss;
  __syncthreads();
  const float rn = rsqrtf(fmaxf(sred[0] + sred[1], 1e-24f));
  bf16x4 o;
  o[0] = (__bf16)(v.x * rn); o[1] = (__bf16)(v.y * rn);
  o[2] = (__bf16)(v.z * rn); o[3] = (__bf16)(v.w * rn);
  const int k = 4 * t;
  __bf16* dst = xp + ((size_t)(k >> 5) * NB + b) * BK + (k & 31);
  *reinterpret_cast<bf16x4*>(dst) = o;
}

// ---------------- 2) fp32-accurate target cosine + phi ----------------
__global__ void cosphi_kernel(const float* __restrict__ x, const float* __restrict__ w,
                              const int* __restrict__ tgt,
                              float* __restrict__ cos_t, float* __restrict__ phi_t) {
  const int b = blockIdx.x;
  const int lane = threadIdx.x;                // 0..63
  const int t = tgt[b];
  const float4* xr = reinterpret_cast<const float4*>(x + (size_t)b * ND);
  const float4* wr = reinterpret_cast<const float4*>(w + (size_t)t * ND);
  float dp = 0.f, xs = 0.f, ws = 0.f;
  #pragma unroll
  for (int j = 0; j < 2; ++j) {
    float4 xv = xr[lane * 2 + j];
    float4 wv = wr[lane * 2 + j];
    dp += xv.x*wv.x + xv.y*wv.y + xv.z*wv.z + xv.w*wv.w;
    xs += xv.x*xv.x + xv.y*xv.y + xv.z*xv.z + xv.w*xv.w;
    ws += wv.x*wv.x + wv.y*wv.y + wv.z*wv.z + wv.w*wv.w;
  }
  #pragma unroll
  for (int m = 1; m < 64; m <<= 1) {
    dp += __shfl_xor(dp, m);
    xs += __shfl_xor(xs, m);
    ws += __shfl_xor(ws, m);
  }
  if (lane == 0) {
    float c = dp * rsqrtf(fmaxf(xs, 1e-24f)) * rsqrtf(fmaxf(ws, 1e-24f));
    c = fminf(fmaxf(c, -1.f), 1.f);
    float s = sqrtf(fmaxf(1.f - c * c, 0.f));
    float phi = c * C_COS_M - s * C_SIN_M;
    phi = (c > C_TH) ? phi : (c - C_MM);
    cos_t[b] = c;
    phi_t[b] = phi;
  }
}

// ---------------- 3) fused GEMM + partial sum-exp ----------------
// Block: 512 threads (8 waves). Block tile: all 512 batch rows x 64 classes.
// Wave w owns rows [64w, 64w+64) x all 64 classes: 4x4 tiles of mfma 16x16x32 bf16.
// Weight rows are read from HBM exactly once (fp32), normalized-on-the-fly:
// sumsq accumulated in registers during staging, rsqrt applied in epilogue.
__global__ __launch_bounds__(512) void gemm_lse_kernel(
    const __bf16* __restrict__ xp, const float* __restrict__ w,
    float* __restrict__ gsum) {
  __shared__ __align__(16) __bf16 As[NB * BK];   // 32 KB
  __shared__ __align__(16) __bf16 Bs[CT * BK];   // 4 KB
  __shared__ float wss[CT];

  const int tid  = threadIdx.x;
  const int wv   = tid >> 6;
  const int lane = tid & 63;
  const int bc   = blockIdx.x * CT;

  // weight staging role: row wr (0..63), 16B-part wp (0..7)
  const int wr = tid >> 3;
  const int wp = tid & 7;
  const long long wrow = (long long)min(bc + wr, NC - 1);
  const float4* wsrc = reinterpret_cast<const float4*>(w + wrow * (long long)ND);

  float wsq = 0.f;
  f32x4 acc[4][4] = {};

  const int m_w = wv * 64;
  const int qa  = (lane >> 4) * 8;   // k-offset of this lane's frag
  const int ra  = lane & 15;         // row/col within 16-tile

  for (int i = 0; i < NCHUNK; ++i) {
    __syncthreads();
    // --- stage A chunk (32 KB, contiguous) via async global->LDS, width 16 ---
    {
      const char* g = reinterpret_cast<const char*>(xp)
                      + (size_t)i * (NB * BK * 2) + wv * 1024 + lane * 16;
      char* l = reinterpret_cast<char*>(As) + wv * 1024;   // wave-uniform LDS base
      #pragma unroll
      for (int j = 0; j < 4; ++j) {
        __builtin_amdgcn_global_load_lds((GU*)(g + j * 8192), (LU*)(l + j * 8192),
                                         16, 0, 0);
      }
    }
    // --- stage W chunk: fp32 load, sumsq accumulate, bf16 convert -> LDS ---
    {
      float4 v = wsrc[i * 8 + wp];
      wsq += v.x*v.x + v.y*v.y + v.z*v.z + v.w*v.w;
      bf16x4 pk;
      pk[0] = (__bf16)v.x; pk[1] = (__bf16)v.y;
      pk[2] = (__bf16)v.z; pk[3] = (__bf16)v.w;
      *reinterpret_cast<bf16x4*>(Bs + wr * BK + wp * 4) = pk;
    }
    __syncthreads();

    // --- MFMA: 8 x ds_read_b128 + 16 MFMA per wave per chunk ---
    bf16x8 af[4], bfr[4];
    #pragma unroll
    for (int rt = 0; rt < 4; ++rt)
      af[rt] = *reinterpret_cast<const bf16x8*>(As + (m_w + rt * 16 + ra) * BK + qa);
    #pragma unroll
    for (int ct = 0; ct < 4; ++ct)
      bfr[ct] = *reinterpret_cast<const bf16x8*>(Bs + (ct * 16 + ra) * BK + qa);
    #pragma unroll
    for (int rt = 0; rt < 4; ++rt)
      #pragma unroll
      for (int ct = 0; ct < 4; ++ct)
        acc[rt][ct] = __builtin_amdgcn_mfma_f32_16x16x32_bf16(af[rt], bfr[ct],
                                                              acc[rt][ct], 0, 0, 0);
  }

  // reduce weight sumsq across the 8 lanes sharing a row
  wsq += __shfl_xor(wsq, 1);
  wsq += __shfl_xor(wsq, 2);
  wsq += __shfl_xor(wsq, 4);
  if (wp == 0) wss[wr] = wsq;
  __syncthreads();

  // --- epilogue: cosine = acc * rsqrt(|w|^2); e = exp(64*cos - 64); row-sum ---
  // C/D layout (16x16): col = lane&15, row = (lane>>4)*4 + reg
  const int col_l = lane & 15;
  const int quad  = lane >> 4;
  float rnw[4];
  int   vmask[4];
  #pragma unroll
  for (int ct = 0; ct < 4; ++ct) {
    rnw[ct]   = rsqrtf(fmaxf(wss[ct * 16 + col_l], 1e-24f));
    vmask[ct] = (bc + ct * 16 + col_l) < NC;
  }
  #pragma unroll
  for (int rt = 0; rt < 4; ++rt) {
    #pragma unroll
    for (int r = 0; r < 4; ++r) {
      float es = 0.f;
      #pragma unroll
      for (int ct = 0; ct < 4; ++ct) {
        float cosv = acc[rt][ct][r] * rnw[ct];
        float e = __expf(fmaf(FSCALE, cosv, -FSCALE));
        es += vmask[ct] ? e : 0.f;
      }
      // sum over the 16 columns (lanes within each 16-lane group)
      es += __shfl_xor(es, 1);
      es += __shfl_xor(es, 2);
      es += __shfl_xor(es, 4);
      es += __shfl_xor(es, 8);
      if (col_l == 0) {
        atomicAdd(&gsum[m_w + rt * 16 + quad * 4 + r], es);
      }
    }
  }
}

// ---------------- 4) finalize ----------------
__global__ void finalize_kernel(const float* __restrict__ gsum,
                                const float* __restrict__ cos_t,
                                const float* __restrict__ phi_t,
                                float* __restrict__ out) {
  const int b = threadIdx.x;   // 512
  const float c = cos_t[b];
  const float p = phi_t[b];
  float corr = gsum[b] - __expf(fmaf(FSCALE, c, -FSCALE))
                       + __expf(fmaf(FSCALE, p, -FSCALE));
  corr = fmaxf(corr, 1e-38f);
  float lb = FSCALE + logf(corr) - FSCALE * p;
  #pragma unroll
  for (int m = 1; m < 64; m <<= 1) lb += __shfl_xor(lb, m);
  __shared__ float pr[8];
  if ((b & 63) == 0) pr[b >> 6] = lb;
  __syncthreads();
  if (b == 0) {
    float tot = 0.f;
    #pragma unroll
    for (int j = 0; j < 8; ++j) tot += pr[j];
    out[0] = tot * (1.0f / NB);
  }
}

extern "C" void kernel_launch(void* const* d_in, const int* in_sizes, int n_in,
                              void* d_out, int out_size, void* d_ws, size_t ws_size,
                              hipStream_t stream) {
  const float* x  = (const float*)d_in[0];
  const float* w  = (const float*)d_in[1];
  const int* tgt  = (const int*)d_in[2];
  float* out      = (float*)d_out;

  // workspace layout: xp (512 KB) | gsum (2 KB) | cos_t (2 KB) | phi_t (2 KB)
  __bf16* xp   = (__bf16*)d_ws;
  float* gsum  = (float*)((char*)d_ws + (size_t)NB * ND * 2);
  float* cos_t = gsum + NB;
  float* phi_t = cos_t + NB;

  hipMemsetAsync(gsum, 0, NB * sizeof(float), stream);
  pack_x_kernel<<<NB, 128, 0, stream>>>(x, xp);
  cosphi_kernel<<<NB, 64, 0, stream>>>(x, w, tgt, cos_t, phi_t);
  const int nblk = (NC + CT - 1) / CT;   // 1563
  gemm_lse_kernel<<<nblk, 512, 0, stream>>>(xp, w, gsum);
  finalize_kernel<<<1, 512, 0, stream>>>(gsum, cos_t, phi_t, out);
}